// Round 11
// baseline (274.510 us; speedup 1.0000x reference)
//
#include <hip/hip_runtime.h>

#define DEVFN __device__ __forceinline__

typedef __attribute__((ext_vector_type(4))) float f32x4;
typedef __attribute__((ext_vector_type(16))) float f32x16;
typedef __attribute__((ext_vector_type(8))) short short8;
typedef __attribute__((ext_vector_type(4))) unsigned int uint4v;
typedef __attribute__((ext_vector_type(8))) unsigned short ushort8;

constexpr int CB = 32;
constexpr int CS = 2048;
constexpr int CD = 1024;
constexpr int CU = 1024;
constexpr int CM = CB * CS;   // 65536

DEVFN unsigned f2bf_u(float f) {
    unsigned u = __float_as_uint(f);
    return (u + 0x7FFFu + ((u >> 16) & 1u)) >> 16;   // RNE f32->bf16
}
DEVFN unsigned f2bf_pack(float lo, float hi) {
    return f2bf_u(lo) | (f2bf_u(hi) << 16);
}
DEVFN short8 cvt8(f32x4 a, f32x4 b) {
    uint4v p;
    p[0] = f2bf_pack(a[0], a[1]);
    p[1] = f2bf_pack(a[2], a[3]);
    p[2] = f2bf_pack(b[0], b[1]);
    p[3] = f2bf_pack(b[2], b[3]);
    return __builtin_bit_cast(short8, p);
}
DEVFN float tanh_fast(float x) {
    float e = exp2f(x * 2.885390081777927f);
    return 1.0f - 2.0f * __builtin_amdgcn_rcpf(e + 1.0f);
}

// ---- bias = b1 + b2 + q@W2, two-stage split-D ----
__global__ void k_bias1(const float* __restrict__ q, const float* __restrict__ W2,
                        float* __restrict__ bpart) {
    int dc = blockIdx.x, b = blockIdx.y;   // 8 x 32
    int t = threadIdx.x;                    // 256
    __shared__ float qs[128];
    if (t < 128) qs[t] = q[b * CD + dc * 128 + t];
    __syncthreads();
    float acc0 = 0.f, acc1 = 0.f, acc2 = 0.f, acc3 = 0.f;
    const float* w2 = W2 + (size_t)(dc * 128) * CU + t;
#pragma unroll 4
    for (int d = 0; d < 128; ++d) {
        float qv = qs[d];
        const float* r = w2 + (size_t)d * CU;
        acc0 += qv * r[0];
        acc1 += qv * r[256];
        acc2 += qv * r[512];
        acc3 += qv * r[768];
    }
    float* o = bpart + (size_t)(b * 8 + dc) * CU + t;
    o[0] = acc0; o[256] = acc1; o[512] = acc2; o[768] = acc3;
}

__global__ void k_bias2(const float* __restrict__ bpart, const float* __restrict__ b1,
                        const float* __restrict__ b2, float* __restrict__ bias) {
    int idx = blockIdx.x * 256 + threadIdx.x;   // 32768
    int b = idx >> 10, u = idx & 1023;
    float s = b1[u] + b2[u];
#pragma unroll
    for (int dc = 0; dc < 8; ++dc) s += bpart[(size_t)(b * 8 + dc) * CU + u];
    bias[idx] = s;
}

// ---- pack W1[D][U] f32 -> bf16 for 32x32x16 B frags ----
// fragidx = kt*64 + cb*2 + h ; lane l, elem j:
//   d = kt*32 + h*16 + (l>>5)*8 + j ; u = cb*32 + (l&31)
__global__ void k_packW1(const float* __restrict__ W1, unsigned short* __restrict__ W1p) {
    int tid = blockIdx.x * 256 + threadIdx.x;   // 131072 threads, 8 elems each
    int o8 = tid * 8;
    int l = (o8 >> 3) & 63;
    int fragidx = o8 >> 9;
    int h  = fragidx & 1;
    int cb = (fragidx >> 1) & 31;
    int kt = fragidx >> 6;
    int d0 = kt * 32 + h * 16 + (l >> 5) * 8;
    int u  = cb * 32 + (l & 31);
    ushort8 v;
#pragma unroll
    for (int j = 0; j < 8; ++j)
        v[j] = (unsigned short)f2bf_u(W1[(size_t)(d0 + j) * CU + u]);
    *(ushort8*)(W1p + o8) = v;
}

// ---- fused score GEMM v8: 4-wave blocks (256 thr), tile 128r x 256c,
// wave 128r x 64c via 32x32x16 MFMA (acc[4][2] f32x16 = 128 regs).
// 2 independent blocks/CU -> foreign barrier domain fills stalls (m114).
// A: f32->bf16 reg-stage, write-at-top 3-buffer LDS pipeline (lgkmcnt(2) free,
// one barrier/step). B: global->reg dbuf, compiler-counted vmcnt.
__global__ __launch_bounds__(256, 2) void k_score(
    const float* __restrict__ values, const unsigned short* __restrict__ W1p,
    const float* __restrict__ bias, const float* __restrict__ V,
    float* __restrict__ score4) {
    __shared__ __align__(16) char smem[24576];   // 3 x 8 KB A bufs; red reuses buf0

    const int t = threadIdx.x;
    const int w = t >> 6, l = t & 63;
    const int p = blockIdx.x;                  // 2048 blocks
    const int L = (p & 7) * 256 + (p >> 3);    // bijective XCD swizzle
    const int xt = L >> 2;                     // m-tile 0..511 (4 siblings share)
    const int uc = L & 3;                      // u-chunk 0..3
    const int ph = xt & 31;                    // K-phase rotation (same for siblings)
    const int m0 = xt * 128;
    const int bb = m0 >> 11;                   // batch (128 divides S)

    // A stage: thread t covers row m0 + (t>>1), k-half h = t&1 (16 f32/step)
    const int sRow = t >> 1, sH = t & 1;
    const float* aSrcT = values + (size_t)(m0 + sRow) * CD + sH * 16;
    // LDS frag layout: frag (rb,h) at (rb*2+h)*1024; lane slot (l ^ (h<<1))*16
    const int aWr = ((sRow >> 5) * 2 + sH) * 1024 + (((sRow & 31) ^ (sH << 1)) << 4);
    const int aRd0 = l << 4;                   // h=0 read slot
    const int aRd1 = (l ^ 2) << 4;             // h=1 read slot
    // B: wave w covers cols uc*256 + w*64; 4 frags (dc,h) contiguous 4 KB
    const unsigned short* bBase = W1p + (uc * 8 + w * 2) * 1024 + l * 8;

    f32x16 acc[4][2];
#pragma unroll
    for (int i = 0; i < 4; ++i)
#pragma unroll
        for (int j = 0; j < 2; ++j)
#pragma unroll
            for (int r = 0; r < 16; ++r) acc[i][j][r] = 0.f;

    short8 bF0[4], bF1[4];
    f32x4 hA0, hA1, hA2, hA3;    // held A (16 f32), written at next step top

    // prologue: B(0)->bF0 ; A(0)->buf0 ; A(1)->hold
    {
        const unsigned short* bs = bBase + (size_t)ph * 32768;
#pragma unroll
        for (int jj = 0; jj < 4; ++jj)
            bF0[jj] = *(const short8*)(bs + jj * 512);
        const float* ap = aSrcT + ph * 32;
        hA0 = *(const f32x4*)(ap);
        hA1 = *(const f32x4*)(ap + 4);
        hA2 = *(const f32x4*)(ap + 8);
        hA3 = *(const f32x4*)(ap + 12);
        *(short8*)(smem + aWr) = cvt8(hA0, hA1);
        *(short8*)(smem + aWr + 512) = cvt8(hA2, hA3);
        const int kp1 = (ph + 1) & 31;
        const float* ap1 = aSrcT + kp1 * 32;
        hA0 = *(const f32x4*)(ap1);
        hA1 = *(const f32x4*)(ap1 + 4);
        hA2 = *(const f32x4*)(ap1 + 8);
        hA3 = *(const f32x4*)(ap1 + 12);
    }

    // step KT: write held A(KT+1)->buf[WIDX]; lgkm(2); barrier; load B(KT+1),
    // A(KT+2); ds_read buf[RIDX]; 16x MFMA 32x32x16.
#define SCORE_BODY(KT, RIDX, WIDX, BFC, BFN, DO_WR, DO_LDB, DO_LDA)                 \
    {                                                                               \
        if (DO_WR) {                                                                \
            char* wB = smem + (WIDX) * 8192;                                        \
            *(short8*)(wB + aWr) = cvt8(hA0, hA1);                                  \
            *(short8*)(wB + aWr + 512) = cvt8(hA2, hA3);                            \
        }                                                                           \
        asm volatile("s_waitcnt lgkmcnt(2)" ::: "memory");                          \
        asm volatile("s_barrier" ::: "memory");                                     \
        if (DO_LDB) {                                                               \
            const int kp = ((KT) + 1 + ph) & 31;                                    \
            const unsigned short* bs = bBase + (size_t)kp * 32768;                  \
            _Pragma("unroll")                                                       \
            for (int jj = 0; jj < 4; ++jj)                                          \
                BFN[jj] = *(const short8*)(bs + jj * 512);                          \
        }                                                                           \
        if (DO_LDA) {                                                               \
            const int kp = ((KT) + 2 + ph) & 31;                                    \
            const float* ap = aSrcT + kp * 32;                                      \
            hA0 = *(const f32x4*)(ap);                                              \
            hA1 = *(const f32x4*)(ap + 4);                                          \
            hA2 = *(const f32x4*)(ap + 8);                                          \
            hA3 = *(const f32x4*)(ap + 12);                                         \
        }                                                                           \
        const char* aB = smem + (RIDX) * 8192;                                      \
        short8 aF0[4], aF1[4];                                                      \
        _Pragma("unroll")                                                           \
        for (int rb = 0; rb < 4; ++rb) {                                            \
            aF0[rb] = *(const short8*)(aB + (rb * 2) * 1024 + aRd0);                \
            aF1[rb] = *(const short8*)(aB + (rb * 2 + 1) * 1024 + aRd1);            \
        }                                                                           \
        __builtin_amdgcn_s_setprio(1);                                              \
        _Pragma("unroll")                                                           \
        for (int rb = 0; rb < 4; ++rb)                                              \
            _Pragma("unroll")                                                       \
            for (int cb = 0; cb < 2; ++cb)                                          \
                acc[rb][cb] = __builtin_amdgcn_mfma_f32_32x32x16_bf16(              \
                    aF0[rb], BFC[cb * 2], acc[rb][cb], 0, 0, 0);                    \
        _Pragma("unroll")                                                           \
        for (int rb = 0; rb < 4; ++rb)                                              \
            _Pragma("unroll")                                                       \
            for (int cb = 0; cb < 2; ++cb)                                          \
                acc[rb][cb] = __builtin_amdgcn_mfma_f32_32x32x16_bf16(              \
                    aF1[rb], BFC[cb * 2 + 1], acc[rb][cb], 0, 0, 0);                \
        __builtin_amdgcn_s_setprio(0);                                              \
    }

    for (int kt = 0; kt < 30; kt += 6) {
        SCORE_BODY(kt + 0, 0, 1, bF0, bF1, 1, 1, 1)
        SCORE_BODY(kt + 1, 1, 2, bF1, bF0, 1, 1, 1)
        SCORE_BODY(kt + 2, 2, 0, bF0, bF1, 1, 1, 1)
        SCORE_BODY(kt + 3, 0, 1, bF1, bF0, 1, 1, 1)
        SCORE_BODY(kt + 4, 1, 2, bF0, bF1, 1, 1, (kt + 4 < 30))
        SCORE_BODY(kt + 5, 2, 0, bF1, bF0, 1, 1, (kt + 5 < 30))
    }
    SCORE_BODY(30, 0, 1, bF0, bF1, 1, 1, 0)   // write A(31), load B(31)
    SCORE_BODY(31, 1, 2, bF1, bF0, 0, 0, 0)
#undef SCORE_BODY

    // epilogue: score partial over this wave's 64 cols, rows via C/D map
    // col = base + cb*32 + (l&31); row = rb*32 + (r&3) + 8*(r>>2) + 4*(l>>5)
    float* red = (float*)smem;   // [4][128] f32 = 2 KB in buf0 (no reader left)
    {
        const int col0 = uc * 256 + w * 64 + (l & 31);
        const float v0 = V[col0], v1 = V[col0 + 32];
        const float z0 = bias[bb * CU + col0], z1 = bias[bb * CU + col0 + 32];
#pragma unroll
        for (int rb = 0; rb < 4; ++rb) {
#pragma unroll
            for (int r = 0; r < 16; ++r) {
                float pv = v0 * tanh_fast(acc[rb][0][r] + z0)
                         + v1 * tanh_fast(acc[rb][1][r] + z1);
                pv += __shfl_xor(pv, 1);
                pv += __shfl_xor(pv, 2);
                pv += __shfl_xor(pv, 4);
                pv += __shfl_xor(pv, 8);
                pv += __shfl_xor(pv, 16);
                if ((l & 31) == 0)
                    red[w * 128 + rb * 32 + (r & 3) + 8 * (r >> 2) + 4 * (l >> 5)] = pv;
            }
        }
    }
    __syncthreads();
    if (t < 128) {
        float sv = red[t] + red[128 + t] + red[256 + t] + red[384 + t];
        score4[(size_t)uc * CM + m0 + t] = sv;
    }
}

// ---- softmax over S per batch; sums the 4 u-chunk slices ----
__global__ void k_softmax(const float* __restrict__ score4, float* __restrict__ wts) {
    int b = blockIdx.x, t = threadIdx.x;   // 1024 threads
    int i0 = b * CS + t, i1 = i0 + 1024;
    float s0 = score4[i0] + score4[CM + i0] + score4[2 * CM + i0] + score4[3 * CM + i0];
    float s1 = score4[i1] + score4[CM + i1] + score4[2 * CM + i1] + score4[3 * CM + i1];
    __shared__ float red[16];
    int wv = t >> 6, ln = t & 63;
    float m = fmaxf(s0, s1);
#pragma unroll
    for (int o = 32; o >= 1; o >>= 1) m = fmaxf(m, __shfl_xor(m, o));
    if (ln == 0) red[wv] = m;
    __syncthreads();
    float M = red[0];
#pragma unroll
    for (int k = 1; k < 16; ++k) M = fmaxf(M, red[k]);
    float e0 = __expf(s0 - M), e1 = __expf(s1 - M);
    float sm = e0 + e1;
#pragma unroll
    for (int o = 32; o >= 1; o >>= 1) sm += __shfl_xor(sm, o);
    __syncthreads();
    if (ln == 0) red[wv] = sm;
    __syncthreads();
    float T = 0.f;
#pragma unroll
    for (int k = 0; k < 16; ++k) T += red[k];
    float inv = 1.0f / T;
    wts[i0] = e0 * inv;
    wts[i1] = e1 * inv;
}

// ---- context ----
__global__ void k_ctx_part(const float* __restrict__ values, const float* __restrict__ wts,
                           float* __restrict__ part) {
    int b = blockIdx.y, sc = blockIdx.x;   // 32 x 32
    int t = threadIdx.x;                    // 256, float4 each -> full D
    const float* vb = values + ((size_t)b * CS + sc * 64) * CD + t * 4;
    const float* wb = wts + b * CS + sc * 64;
    f32x4 a = {0.f, 0.f, 0.f, 0.f};
#pragma unroll 8
    for (int s = 0; s < 64; ++s) {
        float wgt = wb[s];
        f32x4 v = *(const f32x4*)(vb + (size_t)s * CD);
        a += v * wgt;
    }
    *(f32x4*)(part + (size_t)(b * 32 + sc) * CD + t * 4) = a;
}

__global__ void k_ctx_red(const float* __restrict__ part, float* __restrict__ ctx) {
    int idx = blockIdx.x * 256 + threadIdx.x;   // 32768
    int b = idx >> 10, d = idx & 1023;
    float s = 0.f;
#pragma unroll 8
    for (int c = 0; c < 32; ++c) s += part[(size_t)(b * 32 + c) * CD + d];
    ctx[idx] = s;
}

extern "C" void kernel_launch(void* const* d_in, const int* in_sizes, int n_in,
                              void* d_out, int out_size, void* d_ws, size_t ws_size,
                              hipStream_t stream) {
    const float* query  = (const float*)d_in[0];
    const float* values = (const float*)d_in[1];
    const float* W1     = (const float*)d_in[2];
    const float* b1     = (const float*)d_in[3];
    const float* W2     = (const float*)d_in[4];
    const float* b2     = (const float*)d_in[5];
    const float* V      = (const float*)d_in[6];
    // d_in[7] = bV: softmax shift-invariant, score not an output -> unused

    float* out = (float*)d_out;
    float* ctx = out;            // [32][1024]
    float* wts = out + 32768;    // [32][2048]

    char* ws = (char*)d_ws;
    float*          score4 = (float*)ws;                                       // 1 MB
    float*          bias   = (float*)(ws + (1 << 20));                         // 128 KB
    unsigned short* W1p    = (unsigned short*)(ws + (1 << 20) + (1 << 17));    // 2 MB
    float*          part   = (float*)(ws + (1 << 20) + (1 << 17) + (1 << 21)); // 4 MB
    float*          bpart  = part;   // 1 MB, consumed before k_ctx_part

    k_bias1<<<dim3(8, 32), 256, 0, stream>>>(query, W2, bpart);
    k_bias2<<<128, 256, 0, stream>>>(bpart, b1, b2, bias);
    k_packW1<<<512, 256, 0, stream>>>(W1, W1p);
    k_score<<<2048, 256, 0, stream>>>(values, W1p, bias, V, score4);
    k_softmax<<<32, 1024, 0, stream>>>(score4, wts);
    k_ctx_part<<<dim3(32, 32), 256, 0, stream>>>(values, wts, part);
    k_ctx_red<<<128, 256, 0, stream>>>(part, ctx);
}

// Round 12
// 230.986 us; speedup vs baseline: 1.1884x; 1.1884x over previous
//
#include <hip/hip_runtime.h>

#define DEVFN __device__ __forceinline__

typedef __attribute__((ext_vector_type(4))) float f32x4;
typedef __attribute__((ext_vector_type(8))) short short8;
typedef __attribute__((ext_vector_type(4))) unsigned int uint4v;
typedef __attribute__((ext_vector_type(8))) unsigned short ushort8;

constexpr int CB = 32;
constexpr int CS = 2048;
constexpr int CD = 1024;
constexpr int CU = 1024;
constexpr int CM = CB * CS;   // 65536

DEVFN unsigned f2bf_u(float f) {
    unsigned u = __float_as_uint(f);
    return (u + 0x7FFFu + ((u >> 16) & 1u)) >> 16;   // RNE f32->bf16
}
DEVFN unsigned f2bf_pack(float lo, float hi) {
    return f2bf_u(lo) | (f2bf_u(hi) << 16);
}
DEVFN short8 cvt8(f32x4 a, f32x4 b) {
    uint4v p;
    p[0] = f2bf_pack(a[0], a[1]);
    p[1] = f2bf_pack(a[2], a[3]);
    p[2] = f2bf_pack(b[0], b[1]);
    p[3] = f2bf_pack(b[2], b[3]);
    return __builtin_bit_cast(short8, p);
}
DEVFN float tanh_fast(float x) {
    float e = exp2f(x * 2.885390081777927f);
    return 1.0f - 2.0f * __builtin_amdgcn_rcpf(e + 1.0f);
}

// ---- bias = b1 + b2 + q@W2, two-stage split-D ----
__global__ void k_bias1(const float* __restrict__ q, const float* __restrict__ W2,
                        float* __restrict__ bpart) {
    int dc = blockIdx.x, b = blockIdx.y;   // 8 x 32
    int t = threadIdx.x;                    // 256
    __shared__ float qs[128];
    if (t < 128) qs[t] = q[b * CD + dc * 128 + t];
    __syncthreads();
    float acc0 = 0.f, acc1 = 0.f, acc2 = 0.f, acc3 = 0.f;
    const float* w2 = W2 + (size_t)(dc * 128) * CU + t;
#pragma unroll 4
    for (int d = 0; d < 128; ++d) {
        float qv = qs[d];
        const float* r = w2 + (size_t)d * CU;
        acc0 += qv * r[0];
        acc1 += qv * r[256];
        acc2 += qv * r[512];
        acc3 += qv * r[768];
    }
    float* o = bpart + (size_t)(b * 8 + dc) * CU + t;
    o[0] = acc0; o[256] = acc1; o[512] = acc2; o[768] = acc3;
}

__global__ void k_bias2(const float* __restrict__ bpart, const float* __restrict__ b1,
                        const float* __restrict__ b2, float* __restrict__ bias) {
    int idx = blockIdx.x * 256 + threadIdx.x;   // 32768
    int b = idx >> 10, u = idx & 1023;
    float s = b1[u] + b2[u];
#pragma unroll
    for (int dc = 0; dc < 8; ++dc) s += bpart[(size_t)(b * 8 + dc) * CU + u];
    bias[idx] = s;
}

// ---- pack W1[D][U] f32 -> bf16, MFMA-B fragment-linear tiles (16x16x32) ----
// idx = (kt*4+ut)*8192 + ub*512 + l*8 + j ; d = kt*32 + (l>>4)*8 + j ; u = ut*256 + ub*16 + (l&15)
__global__ void k_packW1(const float* __restrict__ W1, unsigned short* __restrict__ W1p) {
    int tid = blockIdx.x * 256 + threadIdx.x;   // 131072 threads, 8 elems each
    int o8  = tid * 8;
    int l   = (o8 >> 3) & 63;
    int ub  = (o8 >> 9) & 15;
    int ut  = (o8 >> 13) & 3;
    int kt  = o8 >> 15;
    int u  = ut * 256 + ub * 16 + (l & 15);
    int d0 = kt * 32 + (l >> 4) * 8;
    ushort8 v;
#pragma unroll
    for (int j = 0; j < 8; ++j)
        v[j] = (unsigned short)f2bf_u(W1[(size_t)(d0 + j) * CU + u]);
    *(ushort8*)(W1p + o8) = v;
}

// ---- fused score GEMM v9 == r10 structure, 4-wave blocks for 2 blocks/CU.
// Tile 128r x 256c, wave 128r x 64c (acc[8][4]=128 AGPR). 3-buffer A-LDS
// pipeline, counted lgkmcnt(2), ONE barrier/step, proven zero-conflict XOR
// swizzle. B global->reg dbuf, compiler-counted vmcnt. Two independent
// barrier domains per CU fill each other's stalls (m114).
__global__ __launch_bounds__(256, 2) void k_score(
    const float* __restrict__ values, const unsigned short* __restrict__ W1p,
    const float* __restrict__ bias, const float* __restrict__ V,
    float* __restrict__ score4) {
    __shared__ __align__(16) char smem[24576];   // 3 x 8 KB A bufs; red reuses buf0

    const int t = threadIdx.x;
    const int w = t >> 6, l = t & 63;
    const int p = blockIdx.x;                  // 2048 blocks
    const int L = (p & 7) * 256 + (p >> 3);    // bijective XCD swizzle
    const int xt = L >> 2;                     // m-tile 0..511 (4 siblings share A)
    const int uc = L & 3;                      // u-chunk 0..3
    const int ph = xt & 31;                    // K-phase rotation (same for siblings)
    const int m0 = xt * 128;
    const int bb = m0 >> 11;                   // batch (128 divides S)

    // A reg-stage: thread t covers row m0 + (t>>1), k-half sH = t&1 (16 f32/step)
    const int sRow = t >> 1, sH = t & 1;
    const float* aSrcT = values + (size_t)(m0 + sRow) * CD + sH * 16;
    // frag-linear bf16 LDS, XOR swizzle sw(ll) = ll ^ (((ll>>4)&3)<<1)  (<=2-way, r10-proven)
    const int c0 = sH * 2, c1 = sH * 2 + 1;
    const int ll0 = (sRow & 15) | (c0 << 4), ll1 = (sRow & 15) | (c1 << 4);
    const int aWr0 = (sRow >> 4) * 1024 + ((ll0 ^ (((ll0 >> 4) & 3) << 1)) << 4);
    const int aWr1 = (sRow >> 4) * 1024 + ((ll1 ^ (((ll1 >> 4) & 3) << 1)) << 4);
    const int aRd = (l ^ (((l >> 4) & 3) << 1)) << 4;
    // B: wave w covers cols uc*256 + w*64 (4 frags of 1KB, coalesced); ut = uc
    const unsigned short* bBase = W1p + (size_t)uc * 8192 + w * 2048 + l * 8;

    f32x4 acc[8][4];
#pragma unroll
    for (int i = 0; i < 8; ++i)
#pragma unroll
        for (int j = 0; j < 4; ++j) acc[i][j] = f32x4{0.f, 0.f, 0.f, 0.f};

    short8 bF0[4], bF1[4];
    f32x4 hX0, hX1, hX2, hX3, hY0, hY1, hY2, hY3;   // two 16-f32 A holds
    char* ldsR = (char*)smem;            // read buf for step s    = s%3
    char* ldsW = (char*)smem + 16384;    // write buf for step s   = (s+2)%3

    // prologue: B(0)->bF0 ; A(0)->buf0 ; A(1)->buf1 ; A(2)->hX ; drain ; barrier
    {
        const int k0 = ph, k1 = (ph + 1) & 31, k2 = (ph + 2) & 31;
        const unsigned short* bs = bBase + (size_t)k0 * 32768;
#pragma unroll
        for (int jj = 0; jj < 4; ++jj)
            bF0[jj] = *(const short8*)(bs + jj * 512);
        const float* ap = aSrcT + k0 * 32;
        hX0 = *(const f32x4*)(ap);
        hX1 = *(const f32x4*)(ap + 4);
        hX2 = *(const f32x4*)(ap + 8);
        hX3 = *(const f32x4*)(ap + 12);
        *(short8*)(smem + aWr0) = cvt8(hX0, hX1);
        *(short8*)(smem + aWr1) = cvt8(hX2, hX3);
        const float* ap1 = aSrcT + k1 * 32;
        hX0 = *(const f32x4*)(ap1);
        hX1 = *(const f32x4*)(ap1 + 4);
        hX2 = *(const f32x4*)(ap1 + 8);
        hX3 = *(const f32x4*)(ap1 + 12);
        *(short8*)(smem + 8192 + aWr0) = cvt8(hX0, hX1);
        *(short8*)(smem + 8192 + aWr1) = cvt8(hX2, hX3);
        const float* ap2 = aSrcT + k2 * 32;
        hX0 = *(const f32x4*)(ap2);
        hX1 = *(const f32x4*)(ap2 + 4);
        hX2 = *(const f32x4*)(ap2 + 8);
        hX3 = *(const f32x4*)(ap2 + 12);
        asm volatile("s_waitcnt lgkmcnt(0)" ::: "memory");
        asm volatile("s_barrier" ::: "memory");
    }

    // step s: lgkmcnt(2) [buf s+1 writes retired, buf s+2 writes may fly];
    // barrier; load B(s+1), A(s+3)->PL; ds_read buf s; 32x MFMA; write held
    // A(s+2)=PW -> buf (s+2)%3; rotate.
#define SCORE_BODY(KT, BFC, BFN, PW0, PW1, PW2, PW3, PL0, PL1, PL2, PL3,            \
                   DO_LDB, DO_LDA, DO_WR)                                           \
    {                                                                               \
        asm volatile("s_waitcnt lgkmcnt(2)" ::: "memory");                          \
        asm volatile("s_barrier" ::: "memory");                                     \
        if (DO_LDB) {                                                               \
            const int kp = ((KT) + 1 + ph) & 31;                                    \
            const unsigned short* bs = bBase + (size_t)kp * 32768;                  \
            _Pragma("unroll")                                                       \
            for (int jj = 0; jj < 4; ++jj)                                          \
                BFN[jj] = *(const short8*)(bs + jj * 512);                          \
        }                                                                           \
        if (DO_LDA) {                                                               \
            const int kp = ((KT) + 3 + ph) & 31;                                    \
            const float* ap = aSrcT + kp * 32;                                      \
            PL0 = *(const f32x4*)(ap);                                              \
            PL1 = *(const f32x4*)(ap + 4);                                          \
            PL2 = *(const f32x4*)(ap + 8);                                          \
            PL3 = *(const f32x4*)(ap + 12);                                         \
        }                                                                           \
        short8 aF[8];                                                               \
        _Pragma("unroll")                                                           \
        for (int i = 0; i < 8; ++i)                                                 \
            aF[i] = *(const short8*)(ldsR + i * 1024 + aRd);                        \
        __builtin_amdgcn_s_setprio(1);                                              \
        _Pragma("unroll")                                                           \
        for (int i = 0; i < 8; ++i)                                                 \
            _Pragma("unroll")                                                       \
            for (int j = 0; j < 4; ++j)                                             \
                acc[i][j] = __builtin_amdgcn_mfma_f32_16x16x32_bf16(                \
                    aF[i], BFC[j], acc[i][j], 0, 0, 0);                             \
        __builtin_amdgcn_s_setprio(0);                                              \
        if (DO_WR) {                                                                \
            *(short8*)(ldsW + aWr0) = cvt8(PW0, PW1);                               \
            *(short8*)(ldsW + aWr1) = cvt8(PW2, PW3);                               \
        }                                                                           \
        ldsW = ldsR;                                                                \
        ldsR = (ldsR == (char*)smem + 16384) ? (char*)smem : ldsR + 8192;           \
    }

    for (int kt = 0; kt < 28; kt += 2) {
        SCORE_BODY(kt,     bF0, bF1, hX0, hX1, hX2, hX3, hY0, hY1, hY2, hY3, 1, 1, 1)
        SCORE_BODY(kt + 1, bF1, bF0, hY0, hY1, hY2, hY3, hX0, hX1, hX2, hX3, 1, 1, 1)
    }
    SCORE_BODY(28, bF0, bF1, hX0, hX1, hX2, hX3, hY0, hY1, hY2, hY3, 1, 1, 1)   // wr A(30), ld A(31)->hY
    SCORE_BODY(29, bF1, bF0, hY0, hY1, hY2, hY3, hX0, hX1, hX2, hX3, 1, 0, 1)   // wr A(31)=hY
    SCORE_BODY(30, bF0, bF1, hX0, hX1, hX2, hX3, hY0, hY1, hY2, hY3, 1, 0, 0)
    SCORE_BODY(31, bF1, bF0, hY0, hY1, hY2, hY3, hX0, hX1, hX2, hX3, 0, 0, 0)
#undef SCORE_BODY

    // epilogue: partial over this wave's 64 cols, all 128 rows
    float part[8][4];
#pragma unroll
    for (int i = 0; i < 8; ++i)
#pragma unroll
        for (int rr = 0; rr < 4; ++rr) part[i][rr] = 0.f;

#pragma unroll
    for (int j = 0; j < 4; ++j) {
        const int col = uc * 256 + w * 64 + j * 16 + (l & 15);
        const float vv = V[col];
        const float bz = bias[bb * CU + col];
#pragma unroll
        for (int i = 0; i < 8; ++i)
#pragma unroll
            for (int rr = 0; rr < 4; ++rr)
                part[i][rr] += vv * tanh_fast(acc[i][j][rr] + bz);
    }

    __syncthreads();
    float* red = (float*)smem;   // [4][128] f32 = 2 KB
#pragma unroll
    for (int i = 0; i < 8; ++i)
#pragma unroll
        for (int rr = 0; rr < 4; ++rr) {
            float v = part[i][rr];
            v += __shfl_xor(v, 1);
            v += __shfl_xor(v, 2);
            v += __shfl_xor(v, 4);
            v += __shfl_xor(v, 8);
            if ((l & 15) == 0)
                red[w * 128 + i * 16 + (l >> 4) * 4 + rr] = v;
        }
    __syncthreads();
    if (t < 128) {
        float sv = red[t] + red[128 + t] + red[256 + t] + red[384 + t];
        score4[(size_t)uc * CM + m0 + t] = sv;
    }
}

// ---- softmax over S per batch; sums the 4 u-chunk slices ----
__global__ void k_softmax(const float* __restrict__ score4, float* __restrict__ wts) {
    int b = blockIdx.x, t = threadIdx.x;   // 1024 threads
    int i0 = b * CS + t, i1 = i0 + 1024;
    float s0 = score4[i0] + score4[CM + i0] + score4[2 * CM + i0] + score4[3 * CM + i0];
    float s1 = score4[i1] + score4[CM + i1] + score4[2 * CM + i1] + score4[3 * CM + i1];
    __shared__ float red[16];
    int wv = t >> 6, ln = t & 63;
    float m = fmaxf(s0, s1);
#pragma unroll
    for (int o = 32; o >= 1; o >>= 1) m = fmaxf(m, __shfl_xor(m, o));
    if (ln == 0) red[wv] = m;
    __syncthreads();
    float M = red[0];
#pragma unroll
    for (int k = 1; k < 16; ++k) M = fmaxf(M, red[k]);
    float e0 = __expf(s0 - M), e1 = __expf(s1 - M);
    float sm = e0 + e1;
#pragma unroll
    for (int o = 32; o >= 1; o >>= 1) sm += __shfl_xor(sm, o);
    __syncthreads();
    if (ln == 0) red[wv] = sm;
    __syncthreads();
    float T = 0.f;
#pragma unroll
    for (int k = 0; k < 16; ++k) T += red[k];
    float inv = 1.0f / T;
    wts[i0] = e0 * inv;
    wts[i1] = e1 * inv;
}

// ---- context ----
__global__ void k_ctx_part(const float* __restrict__ values, const float* __restrict__ wts,
                           float* __restrict__ part) {
    int b = blockIdx.y, sc = blockIdx.x;   // 32 x 32
    int t = threadIdx.x;                    // 256, float4 each -> full D
    const float* vb = values + ((size_t)b * CS + sc * 64) * CD + t * 4;
    const float* wb = wts + b * CS + sc * 64;
    f32x4 a = {0.f, 0.f, 0.f, 0.f};
#pragma unroll 8
    for (int s = 0; s < 64; ++s) {
        float wgt = wb[s];
        f32x4 v = *(const f32x4*)(vb + (size_t)s * CD);
        a += v * wgt;
    }
    *(f32x4*)(part + (size_t)(b * 32 + sc) * CD + t * 4) = a;
}

__global__ void k_ctx_red(const float* __restrict__ part, float* __restrict__ ctx) {
    int idx = blockIdx.x * 256 + threadIdx.x;   // 32768
    int b = idx >> 10, d = idx & 1023;
    float s = 0.f;
#pragma unroll 8
    for (int c = 0; c < 32; ++c) s += part[(size_t)(b * 32 + c) * CD + d];
    ctx[idx] = s;
}

extern "C" void kernel_launch(void* const* d_in, const int* in_sizes, int n_in,
                              void* d_out, int out_size, void* d_ws, size_t ws_size,
                              hipStream_t stream) {
    const float* query  = (const float*)d_in[0];
    const float* values = (const float*)d_in[1];
    const float* W1     = (const float*)d_in[2];
    const float* b1     = (const float*)d_in[3];
    const float* W2     = (const float*)d_in[4];
    const float* b2     = (const float*)d_in[5];
    const float* V      = (const float*)d_in[6];
    // d_in[7] = bV: softmax shift-invariant, score not an output -> unused

    float* out = (float*)d_out;
    float* ctx = out;            // [32][1024]
    float* wts = out + 32768;    // [32][2048]

    char* ws = (char*)d_ws;
    float*          score4 = (float*)ws;                                       // 1 MB
    float*          bias   = (float*)(ws + (1 << 20));                         // 128 KB
    unsigned short* W1p    = (unsigned short*)(ws + (1 << 20) + (1 << 17));    // 2 MB
    float*          part   = (float*)(ws + (1 << 20) + (1 << 17) + (1 << 21)); // 4 MB
    float*          bpart  = part;   // 1 MB, consumed before k_ctx_part

    k_bias1<<<dim3(8, 32), 256, 0, stream>>>(query, W2, bpart);
    k_bias2<<<128, 256, 0, stream>>>(bpart, b1, b2, bias);
    k_packW1<<<512, 256, 0, stream>>>(W1, W1p);
    k_score<<<2048, 256, 0, stream>>>(values, W1p, bias, V, score4);
    k_softmax<<<32, 1024, 0, stream>>>(score4, wts);
    k_ctx_part<<<dim3(32, 32), 256, 0, stream>>>(values, wts, part);
    k_ctx_red<<<128, 256, 0, stream>>>(part, ctx);
}